// Round 9
// baseline (546.691 us; speedup 1.0000x reference)
//
#include <hip/hip_runtime.h>
#include <hip/hip_bf16.h>

#define NN 100000
#define NE 1250000
#define DD 64
#define RR 16
#define NTILE 6250        // NN/16 dst-tiles
#define NBINS 100000      // (dst>>4)*16 + rel
#define NBLK_SCAN 391     // ceil(NBINS/256) == ceil(NN/256)

typedef __attribute__((ext_vector_type(8))) short s16x8;
typedef __attribute__((ext_vector_type(4))) float f32x4;

static __device__ __forceinline__ unsigned short f2bf(float v) {
    __hip_bfloat16 h = __float2bfloat16(v);
    return __builtin_bit_cast(unsigned short, h);
}
static __device__ __forceinline__ unsigned int pack2(float a, float b) {
    return ((unsigned int)f2bf(b) << 16) | (unsigned int)f2bf(a);
}

// ---------------- sort edges by (dst-tile, rel): counting sort, 100k bins ----------------

__global__ void hist_key(const int* __restrict__ dst, const int* __restrict__ et,
                         int* __restrict__ cnt) {
    int e = blockIdx.x * 256 + threadIdx.x;
    if (e < NE) atomicAdd(&cnt[(dst[e] >> 4) * 16 + et[e]], 1);
}

__global__ __launch_bounds__(256) void scan1(const int* __restrict__ cnt,
                                             int* __restrict__ rp, int* __restrict__ part) {
    __shared__ int s[256];
    int i = blockIdx.x * 256 + threadIdx.x;
    int v = (i < NBINS) ? cnt[i] : 0;
    s[threadIdx.x] = v;
    __syncthreads();
    for (int off = 1; off < 256; off <<= 1) {
        int t = (threadIdx.x >= off) ? s[threadIdx.x - off] : 0;
        __syncthreads();
        s[threadIdx.x] += t;
        __syncthreads();
    }
    if (i < NBINS) rp[i] = s[threadIdx.x] - v;        // exclusive
    if (threadIdx.x == 255) part[blockIdx.x] = s[255];
}

__global__ void scan2(int* __restrict__ part, int* __restrict__ rp) {
    __shared__ int s[NBLK_SCAN];
    if (threadIdx.x < NBLK_SCAN) s[threadIdx.x] = part[threadIdx.x];
    __syncthreads();
    if (threadIdx.x == 0) {
        int acc = 0;
        for (int b = 0; b < NBLK_SCAN; ++b) { int t = s[b]; s[b] = acc; acc += t; }
        rp[NBINS] = NE;
    }
    __syncthreads();
    if (threadIdx.x < NBLK_SCAN) part[threadIdx.x] = s[threadIdx.x];
}

__global__ void scan3(int* __restrict__ rp, const int* __restrict__ part, int* __restrict__ cur) {
    int i = blockIdx.x * 256 + threadIdx.x;
    if (i < NBINS) {
        int v = rp[i] + part[blockIdx.x];
        rp[i] = v;
        cur[i] = v;
    }
}

// ep[p] = src | (dst&15)<<20   (order within bin irrelevant: indicator-MFMA is order-free)
__global__ void scatter_key(const int* __restrict__ src, const int* __restrict__ dst,
                            const int* __restrict__ et, int* __restrict__ cur,
                            unsigned int* __restrict__ ep) {
    int e = blockIdx.x * 256 + threadIdx.x;
    if (e >= NE) return;
    int d = dst[e];
    int p = atomicAdd(&cur[(d >> 4) * 16 + et[e]], 1);
    ep[p] = (unsigned int)src[e] | ((unsigned int)(d & 15) << 20);
}

// ---------------- precision prep ----------------

// wt[l][p][o][d] = bf16( (p<16 ? W_l[p] : sw_l)[d][o] )   (B-operand source: n=o via lane, k=d contiguous)
__global__ void prep_w2(const float* __restrict__ W1, const float* __restrict__ sw1,
                        const float* __restrict__ W2, const float* __restrict__ sw2,
                        unsigned short* __restrict__ wt) {
    int i = blockIdx.x * 256 + threadIdx.x;
    if (i >= 2 * 17 * DD * DD) return;
    int d = i & 63;
    int o = (i >> 6) & 63;
    int p = (i >> 12) % 17;
    int l = i / (17 * DD * DD);
    const float* srcp;
    if (p < 16) srcp = (l ? W2 : W1) + p * DD * DD;
    else        srcp = (l ? sw2 : sw1);
    wt[i] = f2bf(srcp[d * DD + o]);
}

__global__ void prep_x2(const float* __restrict__ x, unsigned short* __restrict__ xb) {
    int i = blockIdx.x * blockDim.x + threadIdx.x;
    if (i < NN * DD) xb[i] = f2bf(x[i]);
}

// ---------------- fused layer: gather -> MFMA1 (msg) -> indicator MFMA2 (per-dst sum) ----------------
// One wave per 16-dst tile. Per (tile, rel) bin, 32-edge superchunks:
//   chunk A: MFMA1 row m holds slot (m>>2)*8+(m&3); chunk B: +4.
//   C1 layout (col=lane&15, row=q*4+v) == B2 slot layout (n=lane&15, k=q*8+j) under this remap.
//   A2[m=dstloc][k=slot] = indicator built from shuffled dst-locals; pads get dstloc=31 -> zero.
// D accumulates the 16x64 output tile in registers across all rels + self plane (p=16).
__global__ __launch_bounds__(256) void fused_layer(
    const unsigned short* __restrict__ xb,   // [N][64] bf16 layer input
    const unsigned short* __restrict__ wt,   // [17][64][64] bf16 (o-major, d inner)
    const int* __restrict__ rp,              // [NBINS+1]
    const unsigned int* __restrict__ ep,     // [E] src | dstloc<<20
    const float* __restrict__ bias,
    const float* __restrict__ xres,          // fp32 residual or nullptr
    unsigned short* __restrict__ outb,       // bf16 out (layer 1) or nullptr
    float* __restrict__ outf)                // fp32 out (layer 2) or nullptr
{
    __shared__ float stage[4][16 * DD];      // 16 KB, wave-private quadrants
    const int wid  = threadIdx.x >> 6;
    const int lane = threadIdx.x & 63;
    const int c = lane & 15;
    const int q = lane >> 4;
    const int tile = blockIdx.x * 4 + wid;
    if (tile >= NTILE) return;
    const int n0 = tile * 16;

    // slot remap for chunk A: row m=c computes slot sA; chunk B: sA+4
    const int sA = ((c >> 2) << 3) + (c & 3);

    f32x4 D[4];
    #pragma unroll
    for (int ob = 0; ob < 4; ++ob) D[ob] = (f32x4){0.f, 0.f, 0.f, 0.f};

    for (int r = 0; r < 17; ++r) {
        int s0, s1;
        if (r < 16) { s0 = rp[tile * 16 + r]; s1 = rp[tile * 16 + r + 1]; }
        else        { s0 = 0; s1 = 16; }     // synthetic self-plane edges
        const unsigned short* wp = wt + r * (DD * DD);

        for (int b0 = s0; b0 < s1; b0 += 32) {
            // decode the two slots this lane loads (rows m=c of chunks A and B)
            int eA = b0 + sA;
            int eB = eA + 4;
            int srcA, srcB, dlA, dlB;
            if (r < 16) {
                unsigned int wa = ep[min(eA, s1 - 1)];
                unsigned int wb = ep[min(eB, s1 - 1)];
                srcA = (int)(wa & 0xFFFFF);
                srcB = (int)(wb & 0xFFFFF);
                dlA = (eA < s1) ? (int)(wa >> 20) : 31;
                dlB = (eB < s1) ? (int)(wb >> 20) : 31;
            } else {
                dlA = (eA < 16) ? eA : 31;
                dlB = (eB < 16) ? eB : 31;
                srcA = n0 + ((eA < 16) ? eA : 0);
                srcB = n0 + ((eB < 16) ? eB : 0);
            }

            // A-frags: x rows (verified R1 layout: m=lane&15, k=q*8+j)
            const unsigned short* xrA = xb + (size_t)srcA * DD + q * 8;
            const unsigned short* xrB = xb + (size_t)srcB * DD + q * 8;
            s16x8 aA0 = *(const s16x8*)(xrA);
            s16x8 aA1 = *(const s16x8*)(xrA + 32);
            s16x8 aB0 = *(const s16x8*)(xrB);
            s16x8 aB1 = *(const s16x8*)(xrB + 32);

            // indicator A2: lane (c,q) reg j = (dstloc[slot q*8+j] == c)
            s16x8 a2;
            #pragma unroll
            for (int j = 0; j < 4; ++j) {
                int dj = __shfl(dlA, q * 4 + j, 64);
                a2[j] = (dj == c) ? (short)0x3F80 : (short)0;
            }
            #pragma unroll
            for (int j = 0; j < 4; ++j) {
                int dj = __shfl(dlB, q * 4 + j, 64);
                a2[j + 4] = (dj == c) ? (short)0x3F80 : (short)0;
            }

            #pragma unroll
            for (int ob = 0; ob < 4; ++ob) {
                const unsigned short* wrow = wp + (ob * 16 + c) * DD + q * 8;
                s16x8 w0 = *(const s16x8*)(wrow);
                s16x8 w1 = *(const s16x8*)(wrow + 32);
                f32x4 cA = {0.f, 0.f, 0.f, 0.f};
                cA = __builtin_amdgcn_mfma_f32_16x16x32_bf16(aA0, w0, cA, 0, 0, 0);
                cA = __builtin_amdgcn_mfma_f32_16x16x32_bf16(aA1, w1, cA, 0, 0, 0);
                f32x4 cB = {0.f, 0.f, 0.f, 0.f};
                cB = __builtin_amdgcn_mfma_f32_16x16x32_bf16(aB0, w0, cB, 0, 0, 0);
                cB = __builtin_amdgcn_mfma_f32_16x16x32_bf16(aB1, w1, cB, 0, 0, 0);
                // B2: k=q*8+j -> chunk A regs (j<4), chunk B regs (j>=4); bf16 repack
                s16x8 b2;
                #pragma unroll
                for (int j = 0; j < 4; ++j) {
                    b2[j]     = (short)f2bf(cA[j]);
                    b2[j + 4] = (short)f2bf(cB[j]);
                }
                D[ob] = __builtin_amdgcn_mfma_f32_16x16x32_bf16(a2, b2, D[ob], 0, 0, 0);
            }
        }
    }

    // epilogue: lane (c,q) reg v of D[ob] -> node n0+q*4+v, channel ob*16+c
    float* ls = stage[wid];
    #pragma unroll
    for (int ob = 0; ob < 4; ++ob) {
        const int ch = ob * 16 + c;
        #pragma unroll
        for (int v = 0; v < 4; ++v) {
            const int node = q * 4 + v;
            float val = D[ob][v] + bias[ch];
            if (xres) val += xres[(size_t)(n0 + node) * DD + ch];
            val = fmaxf(val, 0.f);
            ls[node * DD + ch] = val;
        }
    }
    // drain wave-private stage -> contiguous global stores (no barrier needed)
    if (outb) {
        unsigned short* g = outb + (size_t)n0 * DD;
        #pragma unroll
        for (int j = 0; j < 4; ++j) {
            int i4 = lane + 64 * j;                  // 256 4-elem pieces = 1024 vals
            const float* p = ls + i4 * 4;
            uint2 pk;
            pk.x = pack2(p[0], p[1]);
            pk.y = pack2(p[2], p[3]);
            *(uint2*)(g + (size_t)i4 * 4) = pk;
        }
    }
    if (outf) {
        float* g = outf + (size_t)n0 * DD;
        #pragma unroll
        for (int j = 0; j < 4; ++j) {
            int i4 = lane + 64 * j;
            const float4* p = (const float4*)(ls + i4 * 4);
            *(float4*)(g + (size_t)i4 * 4) = *p;
        }
    }
}

// ================= launch =================

extern "C" void kernel_launch(void* const* d_in, const int* in_sizes, int n_in,
                              void* d_out, int out_size, void* d_ws, size_t ws_size,
                              hipStream_t stream)
{
    (void)in_sizes; (void)n_in; (void)out_size; (void)ws_size;
    const float* x    = (const float*)d_in[0];
    const int*   ei   = (const int*)d_in[1];
    const int*   et   = (const int*)d_in[2];
    const float* W1   = (const float*)d_in[3];
    const float* sw1  = (const float*)d_in[4];
    const float* b1   = (const float*)d_in[5];
    const float* W2   = (const float*)d_in[6];
    const float* sw2  = (const float*)d_in[7];
    const float* b2   = (const float*)d_in[8];
    float* out = (float*)d_out;

    const int* srcA = ei;
    const int* dstA = ei + NE;

    char* ws = (char*)d_ws;
    unsigned short* xb   = (unsigned short*)(ws);                 // 12,800,000
    unsigned short* h1b  = (unsigned short*)(ws + 12800000);      // 12,800,000
    unsigned short* wt2  = (unsigned short*)(ws + 25600000);      //    278,528
    unsigned int*   ep   = (unsigned int*)(ws + 25878528);        //  5,000,000
    int*            rp   = (int*)(ws + 30878528);                 //    400,004
    int*            cnt  = (int*)(ws + 31278544);                 //    400,000
    int*            cur  = (int*)(ws + 31678544);                 //    400,000
    int*            part = (int*)(ws + 32078544);                 //      1,600

    const int NB_E    = (NE + 255) / 256;        // 4883
    const int NB_ELEM = (NN * DD + 255) / 256;   // 25000
    const int WPL = 17 * DD * DD;                // wt2 per-layer stride

    // sort edges by (dst-tile, rel) — once, reused by both layers
    hipMemsetAsync(cnt, 0, NBINS * sizeof(int), stream);
    hist_key<<<NB_E, 256, 0, stream>>>(dstA, et, cnt);
    scan1<<<NBLK_SCAN, 256, 0, stream>>>(cnt, rp, part);
    scan2<<<1, 512, 0, stream>>>(part, rp);
    scan3<<<NBLK_SCAN, 256, 0, stream>>>(rp, part, cur);
    scatter_key<<<NB_E, 256, 0, stream>>>(srcA, dstA, et, cur, ep);

    // precision prep
    prep_w2<<<(2 * 17 * DD * DD + 255) / 256, 256, 0, stream>>>(W1, sw1, W2, sw2, wt2);
    prep_x2<<<NB_ELEM, 256, 0, stream>>>(x, xb);

    const int NB_F = (NTILE + 3) / 4;            // 1563

    // ---- layer 1 (residual) ----
    fused_layer<<<NB_F, 256, 0, stream>>>(xb, wt2, rp, ep, b1, x, h1b, nullptr);
    // ---- layer 2 (no residual) ----
    fused_layer<<<NB_F, 256, 0, stream>>>(h1b, wt2 + WPL, rp, ep, b2, nullptr, nullptr, out);
}

// Round 10
// 491.398 us; speedup vs baseline: 1.1125x; 1.1125x over previous
//
#include <hip/hip_runtime.h>
#include <hip/hip_bf16.h>

#define NN 100000
#define NE 1250000
#define DD 64
#define RR 16
#define NTILE 6250        // NN/16 dst-tiles
#define NBINS 100000      // (dst>>4)*16 + rel
#define NBLK_SCAN 391     // ceil(NBINS/256)
#define EBCAP 512         // staged edges per tile (mean 200, std ~14 -> safe)

typedef __attribute__((ext_vector_type(8))) short s16x8;
typedef __attribute__((ext_vector_type(4))) float f32x4;

static __device__ __forceinline__ unsigned short f2bf(float v) {
    __hip_bfloat16 h = __float2bfloat16(v);
    return __builtin_bit_cast(unsigned short, h);
}
static __device__ __forceinline__ unsigned int pack2(float a, float b) {
    return ((unsigned int)f2bf(b) << 16) | (unsigned int)f2bf(a);
}

// ---------------- sort edges by (dst-tile, rel): counting sort, 100k bins ----------------

__global__ void hist_key(const int* __restrict__ dst, const int* __restrict__ et,
                         int* __restrict__ cnt) {
    int e = blockIdx.x * 256 + threadIdx.x;
    if (e < NE) atomicAdd(&cnt[(dst[e] >> 4) * 16 + et[e]], 1);
}

__global__ __launch_bounds__(256) void scan1(const int* __restrict__ cnt,
                                             int* __restrict__ rp, int* __restrict__ part) {
    __shared__ int s[256];
    int i = blockIdx.x * 256 + threadIdx.x;
    int v = (i < NBINS) ? cnt[i] : 0;
    s[threadIdx.x] = v;
    __syncthreads();
    for (int off = 1; off < 256; off <<= 1) {
        int t = (threadIdx.x >= off) ? s[threadIdx.x - off] : 0;
        __syncthreads();
        s[threadIdx.x] += t;
        __syncthreads();
    }
    if (i < NBINS) rp[i] = s[threadIdx.x] - v;        // exclusive
    if (threadIdx.x == 255) part[blockIdx.x] = s[255];
}

__global__ void scan2(int* __restrict__ part, int* __restrict__ rp) {
    __shared__ int s[NBLK_SCAN];
    if (threadIdx.x < NBLK_SCAN) s[threadIdx.x] = part[threadIdx.x];
    __syncthreads();
    if (threadIdx.x == 0) {
        int acc = 0;
        for (int b = 0; b < NBLK_SCAN; ++b) { int t = s[b]; s[b] = acc; acc += t; }
        rp[NBINS] = NE;
    }
    __syncthreads();
    if (threadIdx.x < NBLK_SCAN) part[threadIdx.x] = s[threadIdx.x];
}

__global__ void scan3(int* __restrict__ rp, const int* __restrict__ part, int* __restrict__ cur) {
    int i = blockIdx.x * 256 + threadIdx.x;
    if (i < NBINS) {
        int v = rp[i] + part[blockIdx.x];
        rp[i] = v;
        cur[i] = v;
    }
}

// ep[p] = src | (dst&15)<<20
__global__ void scatter_key(const int* __restrict__ src, const int* __restrict__ dst,
                            const int* __restrict__ et, int* __restrict__ cur,
                            unsigned int* __restrict__ ep) {
    int e = blockIdx.x * 256 + threadIdx.x;
    if (e >= NE) return;
    int d = dst[e];
    int p = atomicAdd(&cur[(d >> 4) * 16 + et[e]], 1);
    ep[p] = (unsigned int)src[e] | ((unsigned int)(d & 15) << 20);
}

// ---------------- precision prep ----------------

// wt[l][p][o][d] = bf16( (p<16 ? W_l[p] : sw_l)[d][o] )
__global__ void prep_w2(const float* __restrict__ W1, const float* __restrict__ sw1,
                        const float* __restrict__ W2, const float* __restrict__ sw2,
                        unsigned short* __restrict__ wt) {
    int i = blockIdx.x * 256 + threadIdx.x;
    if (i >= 2 * 17 * DD * DD) return;
    int d = i & 63;
    int o = (i >> 6) & 63;
    int p = (i >> 12) % 17;
    int l = i / (17 * DD * DD);
    const float* srcp;
    if (p < 16) srcp = (l ? W2 : W1) + p * DD * DD;
    else        srcp = (l ? sw2 : sw1);
    wt[i] = f2bf(srcp[d * DD + o]);
}

__global__ void prep_x2(const float* __restrict__ x, unsigned short* __restrict__ xb) {
    int i = blockIdx.x * blockDim.x + threadIdx.x;
    if (i < NN * DD) xb[i] = f2bf(x[i]);
}

// ---------------- fused layer: block = 16-dst tile, 4 waves split the 17 planes ----------------
// Per (tile, rel) bin, 32-edge superchunks with CONTIGUOUS assignment:
//   chunk A = edges b0+c, chunk B = edges b0+16+c (skipped when bin rem <= 16).
//   C1 (col=lane&15, row=q*4+v) == B2 slot (n=lane&15, k=q*8+j):
//   slot q*8+j (j<4) -> chunk A row q*4+j; (j>=4) -> chunk B row q*4+(j-4).
//   A2[m=dstloc][k=slot] indicator via shuffles. Partial D combined in LDS.
__global__ __launch_bounds__(256) void fused_layer(
    const unsigned short* __restrict__ xb,   // [N][64] bf16 layer input
    const unsigned short* __restrict__ wt,   // [17][64][64] bf16 (o-major, d inner)
    const int* __restrict__ rp,              // [NBINS+1]
    const unsigned int* __restrict__ ep,     // [E] src | dstloc<<20
    const float* __restrict__ bias,
    const float* __restrict__ xres,          // fp32 residual or nullptr
    unsigned short* __restrict__ outb,       // bf16 out (layer 1) or nullptr
    float* __restrict__ outf)                // fp32 out (layer 2) or nullptr
{
    __shared__ unsigned int eb[EBCAP];       // staged edge list (2 KB)
    __shared__ int rps[17];
    __shared__ float Dred[4 * 1024];         // 16 KB partial-D
    const int tid  = threadIdx.x;
    const int wid  = tid >> 6;
    const int lane = tid & 63;
    const int c = lane & 15;
    const int q = lane >> 4;
    const int tile = blockIdx.x;
    const int n0 = tile * 16;

    if (tid < 17) rps[tid] = rp[tile * 16 + tid];
    __syncthreads();
    const int e0 = rps[0];
    const int cntT = rps[16] - e0;
    const bool inLds = (cntT <= EBCAP);
    const int nst = min(cntT, EBCAP);
    for (int i = tid; i < nst; i += 256) eb[i] = ep[e0 + i];
    __syncthreads();

    f32x4 D[4];
    #pragma unroll
    for (int ob = 0; ob < 4; ++ob) D[ob] = (f32x4){0.f, 0.f, 0.f, 0.f};

    for (int r = wid; r < 17; r += 4) {      // wave0: 0,4,8,12,16(self)
        const unsigned short* wp = wt + r * (DD * DD);
        int s0, s1;
        if (r < 16) { s0 = rps[r]; s1 = rps[r + 1]; } else { s0 = 0; s1 = 16; }

        for (int b0 = s0; b0 < s1; b0 += 32) {
            const int rem = s1 - b0;
            // chunk A: lane c <- edge b0+c
            int srcA, dlA;
            if (r < 16) {
                int eA = min(b0 + c, s1 - 1);
                unsigned int wa = inLds ? eb[eA - e0] : ep[eA];
                srcA = (int)(wa & 0xFFFFF);
                dlA  = (b0 + c < s1) ? (int)(wa >> 20) : 31;
            } else { srcA = n0 + c; dlA = c; }
            const bool hasB = (rem > 16);    // r==16 has rem==16 -> false
            int srcB = srcA, dlB = 31;
            if (hasB) {
                int eB = min(b0 + 16 + c, s1 - 1);
                unsigned int wb = inLds ? eb[eB - e0] : ep[eB];
                srcB = (int)(wb & 0xFFFFF);
                dlB  = (b0 + 16 + c < s1) ? (int)(wb >> 20) : 31;
            }

            const unsigned short* xrA = xb + (size_t)srcA * DD + q * 8;
            s16x8 aA0 = *(const s16x8*)(xrA);
            s16x8 aA1 = *(const s16x8*)(xrA + 32);
            s16x8 aB0, aB1;
            if (hasB) {
                const unsigned short* xrB = xb + (size_t)srcB * DD + q * 8;
                aB0 = *(const s16x8*)(xrB);
                aB1 = *(const s16x8*)(xrB + 32);
            }

            // indicator A2
            s16x8 a2;
            #pragma unroll
            for (int j = 0; j < 4; ++j) {
                int dj = __shfl(dlA, q * 4 + j, 64);
                a2[j] = (dj == c) ? (short)0x3F80 : (short)0;
            }
            if (hasB) {
                #pragma unroll
                for (int j = 0; j < 4; ++j) {
                    int dj = __shfl(dlB, q * 4 + j, 64);
                    a2[j + 4] = (dj == c) ? (short)0x3F80 : (short)0;
                }
            } else {
                #pragma unroll
                for (int j = 0; j < 4; ++j) a2[j + 4] = 0;
            }

            #pragma unroll
            for (int ob = 0; ob < 4; ++ob) {
                const unsigned short* wrow = wp + (ob * 16 + c) * DD + q * 8;
                s16x8 w0 = *(const s16x8*)(wrow);
                s16x8 w1 = *(const s16x8*)(wrow + 32);
                f32x4 cA = {0.f, 0.f, 0.f, 0.f};
                cA = __builtin_amdgcn_mfma_f32_16x16x32_bf16(aA0, w0, cA, 0, 0, 0);
                cA = __builtin_amdgcn_mfma_f32_16x16x32_bf16(aA1, w1, cA, 0, 0, 0);
                s16x8 b2;
                if (hasB) {
                    f32x4 cB = {0.f, 0.f, 0.f, 0.f};
                    cB = __builtin_amdgcn_mfma_f32_16x16x32_bf16(aB0, w0, cB, 0, 0, 0);
                    cB = __builtin_amdgcn_mfma_f32_16x16x32_bf16(aB1, w1, cB, 0, 0, 0);
                    #pragma unroll
                    for (int j = 0; j < 4; ++j) {
                        b2[j]     = (short)f2bf(cA[j]);
                        b2[j + 4] = (short)f2bf(cB[j]);
                    }
                } else {
                    #pragma unroll
                    for (int j = 0; j < 4; ++j) {
                        b2[j]     = (short)f2bf(cA[j]);
                        b2[j + 4] = 0;
                    }
                }
                D[ob] = __builtin_amdgcn_mfma_f32_16x16x32_bf16(a2, b2, D[ob], 0, 0, 0);
            }
        }
    }

    // stage partial D: Dred[wid][node*64 + ch]
    {
        float* dred = Dred + wid * 1024;
        #pragma unroll
        for (int ob = 0; ob < 4; ++ob)
            #pragma unroll
            for (int v = 0; v < 4; ++v)
                dred[(q * 4 + v) * 64 + ob * 16 + c] = D[ob][v];
    }
    __syncthreads();

    // reduce 4 partials + bias (+res) + relu; coalesced stores
    #pragma unroll
    for (int k = 0; k < 2; ++k) {
        int j = k * 512 + tid * 2;
        int node = j >> 6, ch = j & 63;
        float v0 = Dred[j]        + Dred[1024 + j]     + Dred[2048 + j]     + Dred[3072 + j];
        float v1 = Dred[j + 1]    + Dred[1024 + j + 1] + Dred[2048 + j + 1] + Dred[3072 + j + 1];
        v0 += bias[ch];
        v1 += bias[ch + 1];
        if (xres) {
            const float2 rv = *(const float2*)(xres + (size_t)(n0 + node) * DD + ch);
            v0 += rv.x; v1 += rv.y;
        }
        v0 = fmaxf(v0, 0.f);
        v1 = fmaxf(v1, 0.f);
        if (outb)
            *(unsigned int*)(outb + (size_t)(n0 + node) * DD + ch) = pack2(v0, v1);
        if (outf) {
            float2 o = {v0, v1};
            *(float2*)(outf + (size_t)(n0 + node) * DD + ch) = o;
        }
    }
}

// ================= launch =================

extern "C" void kernel_launch(void* const* d_in, const int* in_sizes, int n_in,
                              void* d_out, int out_size, void* d_ws, size_t ws_size,
                              hipStream_t stream)
{
    (void)in_sizes; (void)n_in; (void)out_size; (void)ws_size;
    const float* x    = (const float*)d_in[0];
    const int*   ei   = (const int*)d_in[1];
    const int*   et   = (const int*)d_in[2];
    const float* W1   = (const float*)d_in[3];
    const float* sw1  = (const float*)d_in[4];
    const float* b1   = (const float*)d_in[5];
    const float* W2   = (const float*)d_in[6];
    const float* sw2  = (const float*)d_in[7];
    const float* b2   = (const float*)d_in[8];
    float* out = (float*)d_out;

    const int* srcA = ei;
    const int* dstA = ei + NE;

    char* ws = (char*)d_ws;
    unsigned short* xb   = (unsigned short*)(ws);                 // 12,800,000
    unsigned short* h1b  = (unsigned short*)(ws + 12800000);      // 12,800,000
    unsigned short* wt2  = (unsigned short*)(ws + 25600000);      //    278,528
    unsigned int*   ep   = (unsigned int*)(ws + 25878528);        //  5,000,000
    int*            rp   = (int*)(ws + 30878528);                 //    400,004
    int*            cnt  = (int*)(ws + 31278544);                 //    400,000
    int*            cur  = (int*)(ws + 31678544);                 //    400,000
    int*            part = (int*)(ws + 32078544);                 //      1,600

    const int NB_E    = (NE + 255) / 256;        // 4883
    const int NB_ELEM = (NN * DD + 255) / 256;   // 25000
    const int WPL = 17 * DD * DD;                // wt2 per-layer stride

    // sort edges by (dst-tile, rel) — once, reused by both layers
    hipMemsetAsync(cnt, 0, NBINS * sizeof(int), stream);
    hist_key<<<NB_E, 256, 0, stream>>>(dstA, et, cnt);
    scan1<<<NBLK_SCAN, 256, 0, stream>>>(cnt, rp, part);
    scan2<<<1, 512, 0, stream>>>(part, rp);
    scan3<<<NBLK_SCAN, 256, 0, stream>>>(rp, part, cur);
    scatter_key<<<NB_E, 256, 0, stream>>>(srcA, dstA, et, cur, ep);

    // precision prep
    prep_w2<<<(2 * 17 * DD * DD + 255) / 256, 256, 0, stream>>>(W1, sw1, W2, sw2, wt2);
    prep_x2<<<NB_ELEM, 256, 0, stream>>>(x, xb);

    // ---- layer 1 (residual) ----
    fused_layer<<<NTILE, 256, 0, stream>>>(xb, wt2, rp, ep, b1, x, h1b, nullptr);
    // ---- layer 2 (no residual) ----
    fused_layer<<<NTILE, 256, 0, stream>>>(h1b, wt2 + WPL, rp, ep, b2, nullptr, nullptr, out);
}